// Round 1
// 3261.260 us; speedup vs baseline: 1.2535x; 1.2535x over previous
//
#include <hip/hip_runtime.h>
#include <math.h>

#define LSEQ 2048
#define DMODEL 1024
#define NLAYER 12
#define NVOCAB 50257
#define NPADV 50304          /* 393 * 128 */
#define EDIM 2048
#define NST 16
#define DTRANK 64
#define EPSV 1e-5f
#define NCHUNK 64
#define TCHUNK 32   /* LSEQ / NCHUNK */

typedef __attribute__((ext_vector_type(4))) float float4v;
typedef __attribute__((ext_vector_type(8))) short short8v;
typedef __attribute__((ext_vector_type(4))) unsigned short ushort4v;
typedef unsigned short u16;

__device__ __forceinline__ u16 f2bf(float f) {
    union { float f; unsigned int u; } v; v.f = f;
    unsigned int r = v.u + 0x7FFFu + ((v.u >> 16) & 1u);   // RNE
    return (u16)(r >> 16);
}

__device__ __forceinline__ ushort4v cvt4(float4 a) {
    ushort4v r; r[0] = f2bf(a.x); r[1] = f2bf(a.y); r[2] = f2bf(a.z); r[3] = f2bf(a.w);
    return r;
}

__device__ __forceinline__ short8v pack8(float4 a, float4 b) {
    short8v r;
    r[0] = (short)f2bf(a.x); r[1] = (short)f2bf(a.y); r[2] = (short)f2bf(a.z); r[3] = (short)f2bf(a.w);
    r[4] = (short)f2bf(b.x); r[5] = (short)f2bf(b.y); r[6] = (short)f2bf(b.z); r[7] = (short)f2bf(b.w);
    return r;
}

__device__ __forceinline__ float4v mfma_bf16(short8v a, short8v b, float4v c) {
    return __builtin_amdgcn_mfma_f32_16x16x32_bf16(a, b, c, 0, 0, 0);
}

// async global->LDS, 16 B per lane; LDS dest = wave-uniform base + lane*16
__device__ __forceinline__ void gload_lds16(const void* g, void* l) {
    __builtin_amdgcn_global_load_lds(
        (const __attribute__((address_space(1))) unsigned int*)g,
        (__attribute__((address_space(3))) unsigned int*)l,
        16, 0, 0);
}

// ---------------- embedding gather ----------------
__global__ __launch_bounds__(256) void k_embed(const int* __restrict__ ids,
                                               const float* __restrict__ emb,
                                               float* __restrict__ res) {
    const int t = blockIdx.x;
    const int row = ids[t];
    ((float4*)(res + (size_t)t * DMODEL))[threadIdx.x] =
        ((const float4*)(emb + (size_t)row * DMODEL))[threadIdx.x];
}

// ---------------- residual add + rmsnorm -> bf16 h ----------------
template<bool ADD>
__global__ __launch_bounds__(256) void k_addnorm(float* __restrict__ res,
                                                 const float* __restrict__ xin,
                                                 const float* __restrict__ w,
                                                 u16* __restrict__ h) {
    const int t = blockIdx.x;
    const int i = threadIdx.x;
    float4 r = ((float4*)(res + (size_t)t * DMODEL))[i];
    if (ADD) {
        float4 xv = ((const float4*)(xin + (size_t)t * DMODEL))[i];
        r.x += xv.x; r.y += xv.y; r.z += xv.z; r.w += xv.w;
        ((float4*)(res + (size_t)t * DMODEL))[i] = r;
    }
    float ss = r.x * r.x + r.y * r.y + r.z * r.z + r.w * r.w;
#pragma unroll
    for (int off = 32; off > 0; off >>= 1) ss += __shfl_xor(ss, off);
    __shared__ float part[4];
    if ((i & 63) == 0) part[i >> 6] = ss;
    __syncthreads();
    float tot = part[0] + part[1] + part[2] + part[3];
    const float inv = rsqrtf(tot * (1.f / DMODEL) + EPSV);
    float4 wv = ((const float4*)w)[i];
    float4 o;
    o.x = r.x * inv * wv.x; o.y = r.y * inv * wv.y;
    o.z = r.z * inv * wv.z; o.w = r.w * inv * wv.w;
    ((ushort4v*)(h + (size_t)t * DMODEL))[i] = cvt4(o);
}

// ---------------- fp32 -> bf16 weight conversion (with zero pad) ----------------
__global__ __launch_bounds__(256) void k_cvt(const float* __restrict__ s, u16* __restrict__ d,
                                             long long n, long long ntot) {
    const long long stride = (long long)gridDim.x * 256 * 8;
    for (long long i = ((long long)blockIdx.x * 256 + threadIdx.x) * 8; i < ntot; i += stride) {
        ushort4v lo, hi;
        if (i < n) {   // n is a multiple of 8, no straddle
            float4 a = *(const float4*)(s + i);
            float4 b = *(const float4*)(s + i + 4);
            lo = cvt4(a); hi = cvt4(b);
        } else {
            lo[0] = lo[1] = lo[2] = lo[3] = 0;
            hi[0] = hi[1] = hi[2] = hi[3] = 0;
        }
        *(ushort4v*)(d + i) = lo;
        *(ushort4v*)(d + i + 4) = hi;
    }
}

// two conversions in one launch (in_proj_w + out_proj_w of a layer)
__global__ __launch_bounds__(256) void k_cvt2(const float* __restrict__ sa, u16* __restrict__ da, long long na,
                                              const float* __restrict__ sb, u16* __restrict__ db, long long nb) {
    const long long tot = na + nb;
    const long long stride = (long long)gridDim.x * 256 * 8;
    for (long long i = ((long long)blockIdx.x * 256 + threadIdx.x) * 8; i < tot; i += stride) {
        const float* s; u16* d; long long o;
        if (i < na) { s = sa; d = da; o = i; } else { s = sb; d = db; o = i - na; }
        float4 a = *(const float4*)(s + o);
        float4 b = *(const float4*)(s + o + 4);
        *(ushort4v*)(d + o) = cvt4(a);
        *(ushort4v*)(d + o + 4) = cvt4(b);
    }
}

// ---------------- bf16 MFMA GEMM: C[M x N] = A[M x K] @ W[N x K]^T ----------------
// m97 structure: TMxTN tile, 256 thr = 4 waves (2x2), bf16 operands staged to LDS
// via global_load_lds dwordx4 (no VGPR round-trip, no cvt), 2 barriers per K-step.
// W must be padded so that N-tiles never read OOB (pad rows are zeros).
template<int TM, int TN>
__global__ __launch_bounds__(256) void k_gemm_bf(const u16* __restrict__ A,
                                                 const u16* __restrict__ W,
                                                 float* __restrict__ C,
                                                 int N, int K, int ldc) {
    constexpr int NI = TM / 32, NJ = TN / 32, CA = TM / 64, CB = TN / 64;
    __shared__ u16 As[TM * 32];
    __shared__ u16 Bs[TN * 32];
    const int tid = threadIdx.x;
    const int lane = tid & 63;
    const int wave = tid >> 6;
    const int l16 = lane & 15;
    const int quad = lane >> 4;
    const int wm = (wave >> 1) * (TM / 2);
    const int wn = (wave & 1) * (TN / 2);
    const int srow = lane >> 2;          // 0..15 row within a 16-row chunk
    const int scol = (lane & 3) * 8;     // bf16 col offset (16 B granules)
    const int bm = blockIdx.x, bn = blockIdx.y;

    const u16* Ab = A + ((size_t)bm * TM + srow) * K + scol;
    const u16* Wb = W + ((size_t)bn * TN + srow) * K + scol;

    float4v acc[NI][NJ];
#pragma unroll
    for (int i = 0; i < NI; ++i)
#pragma unroll
        for (int j = 0; j < NJ; ++j)
#pragma unroll
            for (int r = 0; r < 4; ++r) acc[i][j][r] = 0.f;

    for (int k0 = 0; k0 < K; k0 += 32) {
        // stage A-tile: chunk = 16 rows = 1024 B of LDS = one wave-wide load
#pragma unroll
        for (int c = 0; c < CA; ++c) {
            const int chunk = wave * CA + c;
            gload_lds16(Ab + (size_t)chunk * 16 * K + k0, &As[chunk * 512]);
        }
#pragma unroll
        for (int c = 0; c < CB; ++c) {
            const int chunk = wave * CB + c;
            gload_lds16(Wb + (size_t)chunk * 16 * K + k0, &Bs[chunk * 512]);
        }
        __syncthreads();   // compiler drains vmcnt(0) before s_barrier -> LDS ready
        short8v af[NI], bfr[NJ];
#pragma unroll
        for (int i = 0; i < NI; ++i)
            af[i] = *(const short8v*)&As[(wm + i * 16 + l16) * 32 + quad * 8];
#pragma unroll
        for (int j = 0; j < NJ; ++j)
            bfr[j] = *(const short8v*)&Bs[(wn + j * 16 + l16) * 32 + quad * 8];
#pragma unroll
        for (int i = 0; i < NI; ++i)
#pragma unroll
            for (int j = 0; j < NJ; ++j)
                acc[i][j] = mfma_bf16(af[i], bfr[j], acc[i][j]);
        __syncthreads();   // all waves done reading LDS before next stage overwrites
    }

#pragma unroll
    for (int i = 0; i < NI; ++i) {
        const int row0 = bm * TM + wm + i * 16 + quad * 4;
#pragma unroll
        for (int j = 0; j < NJ; ++j) {
            const int col = bn * TN + wn + j * 16 + l16;
            if (col < N) {
#pragma unroll
                for (int r = 0; r < 4; ++r)
                    C[(size_t)(row0 + r) * ldc + col] = acc[i][j][r];
            }
        }
    }
}

// ---------------- legacy fp32-input GEMM (kept for the small dt projection, K=64) ----------------
template<int EPI>
__global__ __launch_bounds__(256) void k_gemm(const float* __restrict__ A,
                                              const float* __restrict__ W,
                                              float* __restrict__ C,
                                              const float* __restrict__ bias,
                                              int N, int K, int lda, int ldw, int ldc) {
    __shared__ u16 As[128][32];
    __shared__ u16 Bs[128][32];
    const int tid = threadIdx.x;
    const int lane = tid & 63;
    const int wave = tid >> 6;
    const int l16 = lane & 15;
    const int quad = lane >> 4;
    const int wm = (wave >> 1) * 64;
    const int wn = (wave & 1) * 64;
    const int srow = tid >> 3;
    const int scol = (tid & 7) * 4;
    const int bm = blockIdx.x, bn = blockIdx.y;

    const float* Ap = A + (size_t)(bm * 128 + srow) * lda + scol;
    const int gn0 = bn * 128 + srow;

    float4 apf[4], bpf[4];
#pragma unroll
    for (int i = 0; i < 4; ++i) {
        apf[i] = *(const float4*)(Ap + (size_t)(32 * i) * lda);
        const int gn = gn0 + 32 * i;
        bpf[i] = (gn < N) ? *(const float4*)(W + (size_t)gn * ldw + scol)
                          : make_float4(0.f, 0.f, 0.f, 0.f);
    }

    float4v acc[4][4];
#pragma unroll
    for (int i = 0; i < 4; ++i)
#pragma unroll
        for (int j = 0; j < 4; ++j)
#pragma unroll
            for (int r = 0; r < 4; ++r) acc[i][j][r] = 0.f;

    int k0 = 0;
    while (true) {
#pragma unroll
        for (int i = 0; i < 4; ++i) {
            *(ushort4v*)&As[srow + 32 * i][scol] = cvt4(apf[i]);
            *(ushort4v*)&Bs[srow + 32 * i][scol] = cvt4(bpf[i]);
        }
        __syncthreads();
        k0 += 32;
        const bool more = (k0 < K);
        if (more) {
#pragma unroll
            for (int i = 0; i < 4; ++i) {
                apf[i] = *(const float4*)(Ap + (size_t)(32 * i) * lda + k0);
                const int gn = gn0 + 32 * i;
                bpf[i] = (gn < N) ? *(const float4*)(W + (size_t)gn * ldw + scol + k0)
                                  : make_float4(0.f, 0.f, 0.f, 0.f);
            }
        }
        short8v af[4], bfr[4];
#pragma unroll
        for (int i = 0; i < 4; ++i)
            af[i] = *(const short8v*)&As[wm + i * 16 + l16][quad * 8];
#pragma unroll
        for (int j = 0; j < 4; ++j)
            bfr[j] = *(const short8v*)&Bs[wn + j * 16 + l16][quad * 8];
#pragma unroll
        for (int i = 0; i < 4; ++i)
#pragma unroll
            for (int j = 0; j < 4; ++j)
                acc[i][j] = mfma_bf16(af[i], bfr[j], acc[i][j]);
        if (!more) break;
        __syncthreads();
    }

#pragma unroll
    for (int i = 0; i < 4; ++i) {
        const int row0 = bm * 128 + wm + i * 16 + quad * 4;
#pragma unroll
        for (int j = 0; j < 4; ++j) {
            const int col = bn * 128 + wn + j * 16 + l16;
            if (col < N) {
#pragma unroll
                for (int r = 0; r < 4; ++r) {
                    float v = acc[i][j][r];
                    if (EPI == 1) {
                        v += bias[col];
                        v = (v > 20.f) ? v : log1pf(__expf(v));
                    }
                    C[(size_t)(row0 + r) * ldc + col] = v;
                }
            }
        }
    }
}

// ---------------- causal depthwise conv (K=4) + bias + silu ----------------
__global__ __launch_bounds__(256) void k_conv(const float* __restrict__ xz,
                                              const float* __restrict__ cw,
                                              const float* __restrict__ cb,
                                              float* __restrict__ xc) {
    const int e = blockIdx.x * 256 + threadIdx.x;
    const int t0 = blockIdx.y * 8;
    const float w0 = cw[e * 4 + 0], w1 = cw[e * 4 + 1], w2 = cw[e * 4 + 2], w3 = cw[e * 4 + 3];
    const float b = cb[e];
    float xm3 = (t0 >= 3) ? xz[(size_t)(t0 - 3) * (2 * EDIM) + e] : 0.f;
    float xm2 = (t0 >= 2) ? xz[(size_t)(t0 - 2) * (2 * EDIM) + e] : 0.f;
    float xm1 = (t0 >= 1) ? xz[(size_t)(t0 - 1) * (2 * EDIM) + e] : 0.f;
#pragma unroll
    for (int s = 0; s < 8; ++s) {
        const int t = t0 + s;
        const float xt = xz[(size_t)t * (2 * EDIM) + e];
        const float v = w0 * xm3 + w1 * xm2 + w2 * xm1 + w3 * xt + b;
        xc[(size_t)t * EDIM + e] = v / (1.f + __expf(-v));
        xm3 = xm2; xm2 = xm1; xm1 = xt;
    }
}

// ---------------- skinny GEMM: dbc[L x 96] = xc[L x E] @ xpW[96 x E]^T ----------------
__global__ __launch_bounds__(256) void k_xproj(const float* __restrict__ xc,
                                               const float* __restrict__ W,
                                               float* __restrict__ dbc) {
    const int tid = threadIdx.x;
    const int wave = tid >> 6, lane = tid & 63;
    const int l16 = lane & 15, quad = lane >> 4;
    const int m = blockIdx.x * 16 + l16;
    const int kb = wave * (EDIM / 4);
    float4v acc[6];
#pragma unroll
    for (int j = 0; j < 6; ++j)
#pragma unroll
        for (int r = 0; r < 4; ++r) acc[j][r] = 0.f;

    for (int ks = 0; ks < EDIM / 4; ks += 32) {
        const int k = kb + ks + quad * 8;
        const float* ap = xc + (size_t)m * EDIM + k;
        const short8v af = pack8(*(const float4*)ap, *(const float4*)(ap + 4));
#pragma unroll
        for (int j = 0; j < 6; ++j) {
            const float* wp = W + (size_t)(j * 16 + l16) * EDIM + k;
            const short8v bf = pack8(*(const float4*)wp, *(const float4*)(wp + 4));
            acc[j] = mfma_bf16(af, bf, acc[j]);
        }
    }
    __shared__ float red[4][16][96];
#pragma unroll
    for (int j = 0; j < 6; ++j)
#pragma unroll
        for (int r = 0; r < 4; ++r)
            red[wave][quad * 4 + r][j * 16 + l16] = acc[j][r];
    __syncthreads();
    for (int idx = tid; idx < 16 * 96; idx += 256) {
        const int r = idx / 96, c = idx % 96;
        const float s = red[0][r][c] + red[1][r][c] + red[2][r][c] + red[3][r][c];
        dbc[(size_t)(blockIdx.x * 16 + r) * 96 + c] = s;
    }
}

// ---------------- selective scan, 3-phase chunked ----------------
__global__ __launch_bounds__(256) void k_scanA(const float* __restrict__ dt,
                                               const float* __restrict__ xc,
                                               const float* __restrict__ dbc,
                                               const float* __restrict__ Al,
                                               float* __restrict__ hpart,
                                               float* __restrict__ sdtb) {
    const int e = blockIdx.y * 256 + threadIdx.x;
    const int c = blockIdx.x;
    float a[NST];
#pragma unroll
    for (int n = 0; n < NST; ++n) a[n] = -__expf(Al[(size_t)e * NST + n]);
    bool fast = true;
#pragma unroll
    for (int n = 0; n < NST; ++n)
        fast = fast && (fabsf(a[n] + (float)(n + 1)) < 1e-3f * (float)(n + 1));
    __align__(16) float h[NST];
#pragma unroll
    for (int n = 0; n < NST; ++n) h[n] = 0.f;
    float sdt = 0.f;
    const int t0 = c * TCHUNK;
    if (fast) {
        for (int s = 0; s < TCHUNK; ++s) {
            const int t = t0 + s;
            const float d = dt[(size_t)t * EDIM + e];
            const float x = xc[(size_t)t * EDIM + e];
            __align__(16) float Bv[NST];
#pragma unroll
            for (int q = 0; q < 4; ++q)
                *(float4*)&Bv[q * 4] = *(const float4*)&dbc[(size_t)t * 96 + 64 + q * 4];
            const float u = d * x;
            sdt += d;
            const float d1 = __expf(-d);
            float pw = 1.f;
#pragma unroll
            for (int n = 0; n < NST; ++n) { pw *= d1; h[n] = fmaf(pw, h[n], u * Bv[n]); }
        }
    } else {
        for (int s = 0; s < TCHUNK; ++s) {
            const int t = t0 + s;
            const float d = dt[(size_t)t * EDIM + e];
            const float x = xc[(size_t)t * EDIM + e];
            __align__(16) float Bv[NST];
#pragma unroll
            for (int q = 0; q < 4; ++q)
                *(float4*)&Bv[q * 4] = *(const float4*)&dbc[(size_t)t * 96 + 64 + q * 4];
            const float u = d * x;
            sdt += d;
#pragma unroll
            for (int n = 0; n < NST; ++n) h[n] = fmaf(__expf(d * a[n]), h[n], u * Bv[n]);
        }
    }
#pragma unroll
    for (int n = 0; n < NST; n += 4)
        *(float4*)&hpart[((size_t)c * EDIM + e) * NST + n] = *(float4*)&h[n];
    sdtb[(size_t)c * EDIM + e] = sdt;
}

__global__ __launch_bounds__(256) void k_scanB(float* __restrict__ hio,
                                               const float* __restrict__ sdtb,
                                               const float* __restrict__ Al) {
    const int idx = blockIdx.x * 256 + threadIdx.x;   // e*16 + n
    const int e = idx >> 4;
    const float a = -__expf(Al[idx]);
    float carry = 0.f;
    for (int c = 0; c < NCHUNK; ++c) {
        const size_t off = ((size_t)c * EDIM + e) * NST + (idx & 15);
        const float hp = hio[off];
        const float ap = __expf(a * sdtb[(size_t)c * EDIM + e]);
        hio[off] = carry;
        carry = fmaf(ap, carry, hp);
    }
}

__global__ __launch_bounds__(256) void k_scanC(const float* __restrict__ dt,
                                               const float* __restrict__ xc,
                                               const float* __restrict__ dbc,
                                               const float* __restrict__ xz,
                                               const float* __restrict__ Al,
                                               const float* __restrict__ Dl,
                                               const float* __restrict__ hin,
                                               u16* __restrict__ y) {
    const int e = blockIdx.y * 256 + threadIdx.x;
    const int c = blockIdx.x;
    float a[NST];
#pragma unroll
    for (int n = 0; n < NST; ++n) a[n] = -__expf(Al[(size_t)e * NST + n]);
    bool fast = true;
#pragma unroll
    for (int n = 0; n < NST; ++n)
        fast = fast && (fabsf(a[n] + (float)(n + 1)) < 1e-3f * (float)(n + 1));
    __align__(16) float h[NST];
#pragma unroll
    for (int n = 0; n < NST; n += 4)
        *(float4*)&h[n] = *(const float4*)&hin[((size_t)c * EDIM + e) * NST + n];
    const float Dv = Dl[e];
    const int t0 = c * TCHUNK;
    for (int s = 0; s < TCHUNK; ++s) {
        const int t = t0 + s;
        const float d = dt[(size_t)t * EDIM + e];
        const float x = xc[(size_t)t * EDIM + e];
        __align__(16) float Bv[NST], Cv[NST];
#pragma unroll
        for (int q = 0; q < 4; ++q) {
            *(float4*)&Bv[q * 4] = *(const float4*)&dbc[(size_t)t * 96 + 64 + q * 4];
            *(float4*)&Cv[q * 4] = *(const float4*)&dbc[(size_t)t * 96 + 80 + q * 4];
        }
        const float u = d * x;
        float ys = 0.f;
        if (fast) {
            const float d1 = __expf(-d);
            float pw = 1.f;
#pragma unroll
            for (int n = 0; n < NST; ++n) {
                pw *= d1;
                h[n] = fmaf(pw, h[n], u * Bv[n]);
                ys = fmaf(h[n], Cv[n], ys);
            }
        } else {
#pragma unroll
            for (int n = 0; n < NST; ++n) {
                h[n] = fmaf(__expf(d * a[n]), h[n], u * Bv[n]);
                ys = fmaf(h[n], Cv[n], ys);
            }
        }
        const float z = xz[(size_t)t * (2 * EDIM) + EDIM + e];
        const float yv = ys + Dv * x;
        y[(size_t)t * EDIM + e] = f2bf(yv * (z / (1.f + __expf(-z))));
    }
}

extern "C" void kernel_launch(void* const* d_in, const int* in_sizes, int n_in,
                              void* d_out, int out_size, void* d_ws, size_t ws_size,
                              hipStream_t stream) {
    const int*   ids   = (const int*)d_in[0];
    const float* emb   = (const float*)d_in[1];
    const float* inW   = (const float*)d_in[2];
    const float* convW = (const float*)d_in[3];
    const float* convB = (const float*)d_in[4];
    const float* xpW   = (const float*)d_in[5];
    const float* dtW   = (const float*)d_in[6];
    const float* dtB   = (const float*)d_in[7];
    const float* Alog  = (const float*)d_in[8];
    const float* Dpar  = (const float*)d_in[9];
    const float* outW  = (const float*)d_in[10];
    const float* normW = (const float*)d_in[11];
    const float* normF = (const float*)d_in[12];
    const float* headW = (const float*)d_in[13];
    float* out = (float*)d_out;

    // ---- workspace layout (~209 MB) ----
    float* ws    = (float*)d_ws;
    float* res   = ws;                                      // L*D
    float* xzb   = res   + (size_t)LSEQ * DMODEL;           // L*2E
    float* xcb   = xzb   + (size_t)LSEQ * 2 * EDIM;         // L*E
    float* dbcb  = xcb   + (size_t)LSEQ * EDIM;             // L*96
    float* dtb   = dbcb  + (size_t)LSEQ * 96;               // L*E
    float* xob   = dtb   + (size_t)LSEQ * EDIM;             // L*D
    float* hpart = xob   + (size_t)LSEQ * DMODEL;           // NCHUNK*E*NST
    float* sdtb  = hpart + (size_t)NCHUNK * EDIM * NST;     // NCHUNK*E
    u16* hbf  = (u16*)(sdtb + (size_t)NCHUNK * EDIM);       // L*D   bf16
    u16* ybf  = hbf  + (size_t)LSEQ * DMODEL;               // L*E   bf16
    u16* wbf  = ybf  + (size_t)LSEQ * EDIM;                 // NPADV*D bf16 scratch (head / in_w)
    u16* wbf2 = wbf  + (size_t)2 * EDIM * DMODEL;           // out_w slot inside scratch

    k_embed<<<LSEQ, 256, 0, stream>>>(ids, emb, res);

    for (int i = 0; i < NLAYER; ++i) {
        if (i == 0)
            k_addnorm<false><<<LSEQ, 256, 0, stream>>>(res, nullptr, normW, hbf);
        else
            k_addnorm<true><<<LSEQ, 256, 0, stream>>>(res, xob, normW + (size_t)i * DMODEL, hbf);

        // convert this layer's in_proj_w and out_proj_w to bf16
        k_cvt2<<<4096, 256, 0, stream>>>(inW + (size_t)i * 2 * EDIM * DMODEL, wbf,
                                         (long long)2 * EDIM * DMODEL,
                                         outW + (size_t)i * DMODEL * EDIM, wbf2,
                                         (long long)DMODEL * EDIM);

        // xz = h @ in_w^T : (2048 x 4096), K=1024
        k_gemm_bf<128, 128><<<dim3(16, 32), 256, 0, stream>>>(hbf, wbf, xzb,
                2 * EDIM, DMODEL, 2 * EDIM);

        k_conv<<<dim3(8, 256), 256, 0, stream>>>(xzb, convW + (size_t)i * EDIM * 4,
                convB + (size_t)i * EDIM, xcb);

        // dbc = xc @ xp_w^T : (2048 x 96), K=2048
        k_xproj<<<128, 256, 0, stream>>>(xcb, xpW + (size_t)i * 96 * EDIM, dbcb);

        // dt = softplus(dbc[:, :64] @ dt_w^T + dt_b) : (2048 x 2048), K=64
        k_gemm<1><<<dim3(16, 16), 256, 0, stream>>>(dbcb, dtW + (size_t)i * EDIM * DTRANK,
                dtb, dtB + (size_t)i * EDIM, EDIM, DTRANK, 96, DTRANK, EDIM);

        const float* Al = Alog + (size_t)i * EDIM * NST;
        k_scanA<<<dim3(NCHUNK, EDIM / 256), 256, 0, stream>>>(dtb, xcb, dbcb, Al, hpart, sdtb);
        k_scanB<<<(EDIM * NST) / 256, 256, 0, stream>>>(hpart, sdtb, Al);
        k_scanC<<<dim3(NCHUNK, EDIM / 256), 256, 0, stream>>>(dtb, xcb, dbcb, xzb, Al,
                Dpar + (size_t)i * EDIM, hpart, ybf);

        // x = y @ out_w^T : (2048 x 1024), K=2048 — 64x64 tile -> 512 blocks (2/CU)
        k_gemm_bf<64, 64><<<dim3(32, 16), 256, 0, stream>>>(ybf, wbf2, xob,
                DMODEL, EDIM, DMODEL);
    }

    k_addnorm<true><<<LSEQ, 256, 0, stream>>>(res, xob, normF, hbf);

    // head: convert W (padded to 50304 rows, zeros), then bf16 GEMM
    k_cvt<<<4096, 256, 0, stream>>>(headW, wbf,
            (long long)NVOCAB * DMODEL, (long long)NPADV * DMODEL);
    k_gemm_bf<128, 128><<<dim3(16, NPADV / 128), 256, 0, stream>>>(hbf, wbf, out,
            NVOCAB, DMODEL, NVOCAB);
}